// Round 1
// baseline (267.670 us; speedup 1.0000x reference)
//
#include <hip/hip_runtime.h>
#include <hip/hip_bf16.h>

typedef __bf16 bf16x8 __attribute__((ext_vector_type(8)));
typedef __bf16 bf16x4 __attribute__((ext_vector_type(4)));
typedef float  f32x4  __attribute__((ext_vector_type(4)));

#define SCALE_F 0.14433756729740643f

// ---------- async global->LDS 16B helper (m97 idiom) ----------
__device__ __forceinline__ void gload_lds16(const __bf16* g, __bf16* l) {
    __builtin_amdgcn_global_load_lds(
        (const __attribute__((address_space(1))) void*)g,
        (__attribute__((address_space(3))) void*)l,
        16, 0, 0);
}

// ---------- fp32 -> bf16 convert (x) ----------
__global__ void cvt_f32_bf16_kernel(const float* __restrict__ in, __bf16* __restrict__ out, int n) {
    int i = (blockIdx.x * blockDim.x + threadIdx.x) * 4;
    if (i < n) {
        float4 v = *(const float4*)&in[i];
        bf16x4 o;
        o[0] = (__bf16)v.x; o[1] = (__bf16)v.y; o[2] = (__bf16)v.z; o[3] = (__bf16)v.w;
        *(bf16x4*)&out[i] = o;
    }
}

// ---------- transpose [R,C] f32 -> [C,R] bf16 ----------
__global__ void transpose_f32_bf16_kernel(const float* __restrict__ in, __bf16* __restrict__ out,
                                          int R, int C) {
    __shared__ float tile[32][33];
    int c0 = blockIdx.x * 32, r0 = blockIdx.y * 32;
    int tx = threadIdx.x, ty = threadIdx.y;
#pragma unroll
    for (int i = 0; i < 4; ++i)
        tile[ty + i * 8][tx] = in[(size_t)(r0 + ty + i * 8) * C + c0 + tx];
    __syncthreads();
#pragma unroll
    for (int i = 0; i < 4; ++i)
        out[(size_t)(c0 + ty + i * 8) * R + r0 + tx] = (__bf16)tile[tx][ty + i * 8];
}

// ---------- m97-style GEMM: C[M,N] = A[M,K] * B[N,K]^T ----------
// A,B bf16 row-major over K. 128x128 block tile, 4 waves of 64x64, BK=32.
template <bool BF16_OUT>
__global__ __launch_bounds__(256, 2)
void gemm_bt_kernel(const __bf16* __restrict__ A, const __bf16* __restrict__ B,
                    void* __restrict__ C, const float* __restrict__ bias,
                    int M, int N, int K) {
    __shared__ __bf16 sA[128 * 32];
    __shared__ __bf16 sB[128 * 32];

    const int m0 = blockIdx.y * 128;
    const int n0 = blockIdx.x * 128;
    const int t = threadIdx.x;
    const int w = t >> 6, lane = t & 63;
    const int quad = lane >> 4, l15 = lane & 15;
    const int wm = w >> 1, wn = w & 1;

    f32x4 acc[4][4] = {};

    for (int k0 = 0; k0 < K; k0 += 32) {
        // stage A,B tiles: 128 rows x 32 k each, packed [row][32] bf16
#pragma unroll
        for (int half = 0; half < 2; ++half) {
            const int row = half * 64 + w * 16 + (lane >> 2);
            const int kk = k0 + (lane & 3) * 8;
            gload_lds16(A + (size_t)(m0 + row) * K + kk, &sA[half * 2048 + w * 512]);
            gload_lds16(B + (size_t)(n0 + row) * K + kk, &sB[half * 2048 + w * 512]);
        }
        __syncthreads();

        bf16x8 aF[4], bF[4];
#pragma unroll
        for (int mt = 0; mt < 4; ++mt)
            aF[mt] = *(const bf16x8*)&sA[(wm * 64 + mt * 16 + l15) * 32 + quad * 8];
#pragma unroll
        for (int nt = 0; nt < 4; ++nt)
            bF[nt] = *(const bf16x8*)&sB[(wn * 64 + nt * 16 + l15) * 32 + quad * 8];
#pragma unroll
        for (int mt = 0; mt < 4; ++mt)
#pragma unroll
            for (int nt = 0; nt < 4; ++nt)
                acc[mt][nt] = __builtin_amdgcn_mfma_f32_16x16x32_bf16(aF[mt], bF[nt], acc[mt][nt], 0, 0, 0);
        __syncthreads();
    }

    // epilogue: row = m0+wm*64+mt*16+quad*4+r, col = n0+wn*64+nt*16+l15
#pragma unroll
    for (int nt = 0; nt < 4; ++nt) {
        const int col = n0 + wn * 64 + nt * 16 + l15;
        float bv = 0.f;
        if (!BF16_OUT) bv = bias[col];
#pragma unroll
        for (int mt = 0; mt < 4; ++mt) {
#pragma unroll
            for (int r = 0; r < 4; ++r) {
                const int row = m0 + wm * 64 + mt * 16 + quad * 4 + r;
                if (BF16_OUT)
                    ((__bf16*)C)[(size_t)row * N + col] = (__bf16)acc[mt][nt][r];
                else
                    ((float*)C)[(size_t)row * N + col] = acc[mt][nt][r] + bv;
            }
        }
    }
}

// ---------- fused flash attention ----------
// Y1 = flat [8192,2304] bf16 qkv gemm output. raw-reshape: q/k/v each contiguous
// [1024,48] per (b,h) at offsets {0, 6291456, 12582912} + bh*49152.
// Ctx bf16 [B,H,N,dh] flat (== [8192,768] row-major for the final GEMM).
#define VT_STRIDE 136
#define P_STRIDE  136

__global__ __launch_bounds__(256, 2)
void attn_kernel(const __bf16* __restrict__ Y1, __bf16* __restrict__ Ctx) {
    __shared__ __bf16 Vt[2][48 * VT_STRIDE];   // [d][krow], double-buffered
    __shared__ __bf16 Pl[128 * P_STRIDE];      // [q][krow], wave-private rows

    const int bx = blockIdx.x;
    const int bh = bx >> 3, qt = bx & 7;
    const int t = threadIdx.x, w = t >> 6, lane = t & 63;
    const int quad = lane >> 4, l15 = lane & 15;

    const size_t qBase = (size_t)bh * 49152;
    const size_t kBase = 6291456 + qBase;
    const size_t vBase = 12582912 + qBase;

    // Q fragments direct from global: A-layout = Q[m=l15][d=quad*8+j], d padded to 64
    bf16x8 qf[2][2];
#pragma unroll
    for (int mt = 0; mt < 2; ++mt)
#pragma unroll
        for (int ks = 0; ks < 2; ++ks) {
            const int d0 = ks * 32 + quad * 8;
            const int row = qt * 128 + w * 32 + mt * 16 + l15;
            if (d0 < 48)
                qf[mt][ks] = *(const bf16x8*)(Y1 + qBase + (size_t)row * 48 + d0);
            else
                qf[mt][ks] = bf16x8{};
        }

    f32x4 o[2][3] = {};
    float m_run[2][4], l_run[2][4];
#pragma unroll
    for (int mt = 0; mt < 2; ++mt)
#pragma unroll
        for (int r = 0; r < 4; ++r) { m_run[mt][r] = -1e30f; l_run[mt][r] = 0.f; }

    for (int it = 0; it < 8; ++it) {
        const int cur = it & 1;
        const int kv0 = it * 128;

        // stage V -> Vt[cur] transposed: Vt[d][krow]
#pragma unroll
        for (int c = 0; c < 6; ++c) {
            const int chunk = t + c * 256;           // 0..1535
            const int krow = chunk / 12;
            const int dbase = (chunk % 12) * 4;
            bf16x4 v = *(const bf16x4*)(Y1 + vBase + (size_t)(kv0 + krow) * 48 + dbase);
#pragma unroll
            for (int j = 0; j < 4; ++j)
                Vt[cur][(dbase + j) * VT_STRIDE + krow] = v[j];
        }

        // S = Q K^T : K fragments direct from global (B-layout: n=krow, k=d)
        f32x4 s[2][8];
#pragma unroll
        for (int nt = 0; nt < 8; ++nt) {
            const int krow = kv0 + nt * 16 + l15;
            bf16x8 kf0 = *(const bf16x8*)(Y1 + kBase + (size_t)krow * 48 + quad * 8);
            bf16x8 kf1;
            if (quad < 2)
                kf1 = *(const bf16x8*)(Y1 + kBase + (size_t)krow * 48 + 32 + quad * 8);
            else
                kf1 = bf16x8{};
#pragma unroll
            for (int mt = 0; mt < 2; ++mt) {
                f32x4 z = {};
                z = __builtin_amdgcn_mfma_f32_16x16x32_bf16(qf[mt][0], kf0, z, 0, 0, 0);
                s[mt][nt] = __builtin_amdgcn_mfma_f32_16x16x32_bf16(qf[mt][1], kf1, z, 0, 0, 0);
            }
        }

        // online softmax: lane owns rows (quad*4+r + mt*16 + w*32); cols l15+16*nt
#pragma unroll
        for (int mt = 0; mt < 2; ++mt) {
#pragma unroll
            for (int r = 0; r < 4; ++r) {
                float mb = -1e30f;
#pragma unroll
                for (int nt = 0; nt < 8; ++nt) {
                    float v = s[mt][nt][r] * SCALE_F;
                    s[mt][nt][r] = v;
                    mb = fmaxf(mb, v);
                }
#pragma unroll
                for (int off = 1; off < 16; off <<= 1)
                    mb = fmaxf(mb, __shfl_xor(mb, off));
                const float mn = fmaxf(m_run[mt][r], mb);
                const float alpha = __expf(m_run[mt][r] - mn);
                m_run[mt][r] = mn;
                float ls = 0.f;
                const int prow = (w * 32 + mt * 16 + quad * 4 + r) * P_STRIDE + l15;
#pragma unroll
                for (int nt = 0; nt < 8; ++nt) {
                    float p = __expf(s[mt][nt][r] - mn);
                    ls += p;
                    Pl[prow + nt * 16] = (__bf16)p;
                }
#pragma unroll
                for (int off = 1; off < 16; off <<= 1)
                    ls += __shfl_xor(ls, off);
                l_run[mt][r] = l_run[mt][r] * alpha + ls;
#pragma unroll
                for (int d3 = 0; d3 < 3; ++d3)
                    o[mt][d3][r] *= alpha;
            }
        }

        __syncthreads();   // Vt[cur] ready; P rows visible (wave-private anyway)

        // O += P V  (A = P[q][krow] from LDS, B = Vt[d][krow])
        bf16x8 pa[2][4];
#pragma unroll
        for (int mt = 0; mt < 2; ++mt)
#pragma unroll
            for (int ks = 0; ks < 4; ++ks)
                pa[mt][ks] = *(const bf16x8*)&Pl[(w * 32 + mt * 16 + l15) * P_STRIDE + ks * 32 + quad * 8];
#pragma unroll
        for (int nt = 0; nt < 3; ++nt) {
#pragma unroll
            for (int ks = 0; ks < 4; ++ks) {
                bf16x8 vb = *(const bf16x8*)&Vt[cur][(nt * 16 + l15) * VT_STRIDE + ks * 32 + quad * 8];
#pragma unroll
                for (int mt = 0; mt < 2; ++mt)
                    o[mt][nt] = __builtin_amdgcn_mfma_f32_16x16x32_bf16(pa[mt][ks], vb, o[mt][nt], 0, 0, 0);
            }
        }
    }

    // epilogue: Ctx[bh*49152 + row*48 + d] = o / l
#pragma unroll
    for (int mt = 0; mt < 2; ++mt) {
#pragma unroll
        for (int nt = 0; nt < 3; ++nt) {
            const int d = nt * 16 + l15;
#pragma unroll
            for (int r = 0; r < 4; ++r) {
                const int row = qt * 128 + w * 32 + mt * 16 + quad * 4 + r;
                Ctx[qBase + (size_t)row * 48 + d] = (__bf16)(o[mt][nt][r] / l_run[mt][r]);
            }
        }
    }
}

// ---------- launch ----------
extern "C" void kernel_launch(void* const* d_in, const int* in_sizes, int n_in,
                              void* d_out, int out_size, void* d_ws, size_t ws_size,
                              hipStream_t stream) {
    const float* x    = (const float*)d_in[0];   // [8,1024,768]
    const float* Wqkv = (const float*)d_in[1];   // [768,2304]
    const float* Wo   = (const float*)d_in[2];   // [768,768]
    const float* bo   = (const float*)d_in[3];   // [768]
    float* out = (float*)d_out;                  // [8,1024,768]

    char* ws = (char*)d_ws;
    __bf16* Xbf    = (__bf16*)(ws + 0);                 // 8192*768
    __bf16* WqkvT  = (__bf16*)(ws + 12582912);          // 2304*768
    __bf16* WoT    = (__bf16*)(ws + 16121856);          // 768*768
    __bf16* Y1     = (__bf16*)(ws + 17301504);          // 8192*2304
    __bf16* Ctx    = (__bf16*)(ws + 55050240);          // 8192*768

    // pre-pass: convert / transpose
    cvt_f32_bf16_kernel<<<6144, 256, 0, stream>>>(x, Xbf, 8192 * 768);
    transpose_f32_bf16_kernel<<<dim3(72, 24), dim3(32, 8), 0, stream>>>(Wqkv, WqkvT, 768, 2304);
    transpose_f32_bf16_kernel<<<dim3(24, 24), dim3(32, 8), 0, stream>>>(Wo, WoT, 768, 768);

    // QKV GEMM: [8192,2304] bf16
    gemm_bt_kernel<true><<<dim3(18, 64), 256, 0, stream>>>(Xbf, WqkvT, Y1, nullptr, 8192, 2304, 768);

    // fused attention: 128 (b,h) x 8 q-tiles
    attn_kernel<<<1024, 256, 0, stream>>>(Y1, Ctx);

    // output GEMM + bias: fp32 out
    gemm_bt_kernel<false><<<dim3(6, 64), 256, 0, stream>>>(Ctx, WoT, out, bo, 8192, 768, 768);
}

// Round 3
// 259.931 us; speedup vs baseline: 1.0298x; 1.0298x over previous
//
#include <hip/hip_runtime.h>
#include <hip/hip_bf16.h>

typedef __bf16 bf16x8 __attribute__((ext_vector_type(8)));
typedef __bf16 bf16x4 __attribute__((ext_vector_type(4)));
typedef float  f32x4  __attribute__((ext_vector_type(4)));

// SCALE * log2(e): softmax computed in base-2 domain
#define C2LOG 0.20823509f

// ---------- async global->LDS 16B helper (m97 idiom) ----------
__device__ __forceinline__ void gload_lds16(const __bf16* g, __bf16* l) {
    __builtin_amdgcn_global_load_lds(
        (const __attribute__((address_space(1))) void*)g,
        (__attribute__((address_space(3))) void*)l,
        16, 0, 0);
}

// ---------- fp32 -> bf16 convert (x) ----------
__global__ void cvt_f32_bf16_kernel(const float* __restrict__ in, __bf16* __restrict__ out, int n) {
    int i = (blockIdx.x * blockDim.x + threadIdx.x) * 4;
    if (i < n) {
        float4 v = *(const float4*)&in[i];
        bf16x4 o;
        o[0] = (__bf16)v.x; o[1] = (__bf16)v.y; o[2] = (__bf16)v.z; o[3] = (__bf16)v.w;
        *(bf16x4*)&out[i] = o;
    }
}

// ---------- transpose [R,C] f32 -> [C,R] bf16 ----------
__global__ void transpose_f32_bf16_kernel(const float* __restrict__ in, __bf16* __restrict__ out,
                                          int R, int C) {
    __shared__ float tile[32][33];
    int c0 = blockIdx.x * 32, r0 = blockIdx.y * 32;
    int tx = threadIdx.x, ty = threadIdx.y;
#pragma unroll
    for (int i = 0; i < 4; ++i)
        tile[ty + i * 8][tx] = in[(size_t)(r0 + ty + i * 8) * C + c0 + tx];
    __syncthreads();
#pragma unroll
    for (int i = 0; i < 4; ++i)
        out[(size_t)(c0 + ty + i * 8) * R + r0 + tx] = (__bf16)tile[tx][ty + i * 8];
}

// ---------- m97-style GEMM: C[M,N] = A[M,K] * B[N,K]^T ----------
template <bool BF16_OUT>
__global__ __launch_bounds__(256, 2)
void gemm_bt_kernel(const __bf16* __restrict__ A, const __bf16* __restrict__ B,
                    void* __restrict__ C, const float* __restrict__ bias,
                    int M, int N, int K) {
    __shared__ __bf16 sA[128 * 32];
    __shared__ __bf16 sB[128 * 32];

    const int m0 = blockIdx.y * 128;
    const int n0 = blockIdx.x * 128;
    const int t = threadIdx.x;
    const int w = t >> 6, lane = t & 63;
    const int quad = lane >> 4, l15 = lane & 15;
    const int wm = w >> 1, wn = w & 1;

    f32x4 acc[4][4] = {};

    for (int k0 = 0; k0 < K; k0 += 32) {
#pragma unroll
        for (int half = 0; half < 2; ++half) {
            const int row = half * 64 + w * 16 + (lane >> 2);
            const int kk = k0 + (lane & 3) * 8;
            gload_lds16(A + (size_t)(m0 + row) * K + kk, &sA[half * 2048 + w * 512]);
            gload_lds16(B + (size_t)(n0 + row) * K + kk, &sB[half * 2048 + w * 512]);
        }
        __syncthreads();

        bf16x8 aF[4], bF[4];
#pragma unroll
        for (int mt = 0; mt < 4; ++mt)
            aF[mt] = *(const bf16x8*)&sA[(wm * 64 + mt * 16 + l15) * 32 + quad * 8];
#pragma unroll
        for (int nt = 0; nt < 4; ++nt)
            bF[nt] = *(const bf16x8*)&sB[(wn * 64 + nt * 16 + l15) * 32 + quad * 8];
#pragma unroll
        for (int mt = 0; mt < 4; ++mt)
#pragma unroll
            for (int nt = 0; nt < 4; ++nt)
                acc[mt][nt] = __builtin_amdgcn_mfma_f32_16x16x32_bf16(aF[mt], bF[nt], acc[mt][nt], 0, 0, 0);
        __syncthreads();
    }

#pragma unroll
    for (int nt = 0; nt < 4; ++nt) {
        const int col = n0 + wn * 64 + nt * 16 + l15;
        float bv = 0.f;
        if (!BF16_OUT) bv = bias[col];
#pragma unroll
        for (int mt = 0; mt < 4; ++mt) {
#pragma unroll
            for (int r = 0; r < 4; ++r) {
                const int row = m0 + wm * 64 + mt * 16 + quad * 4 + r;
                if (BF16_OUT)
                    ((__bf16*)C)[(size_t)row * N + col] = (__bf16)acc[mt][nt][r];
                else
                    ((float*)C)[(size_t)row * N + col] = acc[mt][nt][r] + bv;
            }
        }
    }
}

// ---------- fused flash attention ----------
// k within a 128-KV tile is PERMUTED: k' = (kk&15)*8 + (kk>>4)  (kk = nt*16+l15).
// P and Vt both use k' columns, so P·V is invariant. This makes each lane's 8
// P-elements per (mt,r) contiguous -> single ds_write_b128.
#define VT_STRIDE 136
#define P_STRIDE  136

__global__ __launch_bounds__(256, 3)
void attn_kernel(const __bf16* __restrict__ Y1, __bf16* __restrict__ Ctx) {
    __shared__ __bf16 Vt[48 * VT_STRIDE];      // [d][k'] single buffer
    __shared__ __bf16 Pl[128 * P_STRIDE];      // [q][k']

    const int bx = blockIdx.x;
    const int bh = bx & 127, qt = bx >> 7;     // XCD swizzle: bx%8 == bh%8
    const int t = threadIdx.x, w = t >> 6, lane = t & 63;
    const int quad = lane >> 4, l15 = lane & 15;

    const size_t qBase = (size_t)bh * 49152;
    const size_t kBase = 6291456 + qBase;
    const size_t vBase = 12582912 + qBase;

    // Q fragments direct from global: A-layout = Q[m=l15][d=quad*8+j], d padded to 64
    bf16x8 qf[2][2];
#pragma unroll
    for (int mt = 0; mt < 2; ++mt)
#pragma unroll
        for (int ks = 0; ks < 2; ++ks) {
            const int d0 = ks * 32 + quad * 8;
            const int row = qt * 128 + w * 32 + mt * 16 + l15;
            if (d0 < 48)
                qf[mt][ks] = *(const bf16x8*)(Y1 + qBase + (size_t)row * 48 + d0);
            else
                qf[mt][ks] = bf16x8{};
        }

    f32x4 o[2][3] = {};
    float m_run[2][4], l_run[2][4];
#pragma unroll
    for (int mt = 0; mt < 2; ++mt)
#pragma unroll
        for (int r = 0; r < 4; ++r) { m_run[mt][r] = -1e30f; l_run[mt][r] = 0.f; }

    for (int it = 0; it < 8; ++it) {
        const int kv0 = it * 128;

        __syncthreads();   // previous iteration's Vt/Pl reads complete

        // stage V -> Vt[d][k']: lanes k'-major -> conflict-free LDS writes
        // chunk 0..767: kp = chunk&127, dbase = (chunk>>7)*8 covers {0,8,...,40}
#pragma unroll
        for (int c = 0; c < 3; ++c) {
            const int chunk = t + c * 256;               // 0..767
            const int kp = chunk & 127;                  // k'
            const int dbase = (chunk >> 7) * 8;          // 0,8,16,24,32,40
            const int kk = (kp >> 3) + ((kp & 7) << 4);  // original row in tile
            bf16x8 v = *(const bf16x8*)(Y1 + vBase + (size_t)(kv0 + kk) * 48 + dbase);
#pragma unroll
            for (int j = 0; j < 8; ++j)
                Vt[(dbase + j) * VT_STRIDE + kp] = v[j];
        }

        // S = Q K^T : K fragments direct from global (B-layout: n=kk, k=d)
        f32x4 s[2][8];
#pragma unroll
        for (int nt = 0; nt < 8; ++nt) {
            const int krow = kv0 + nt * 16 + l15;
            bf16x8 kf0 = *(const bf16x8*)(Y1 + kBase + (size_t)krow * 48 + quad * 8);
            bf16x8 kf1;
            if (quad < 2)
                kf1 = *(const bf16x8*)(Y1 + kBase + (size_t)krow * 48 + 32 + quad * 8);
            else
                kf1 = bf16x8{};
#pragma unroll
            for (int mt = 0; mt < 2; ++mt) {
                f32x4 z = {};
                z = __builtin_amdgcn_mfma_f32_16x16x32_bf16(qf[mt][0], kf0, z, 0, 0, 0);
                s[mt][nt] = __builtin_amdgcn_mfma_f32_16x16x32_bf16(qf[mt][1], kf1, z, 0, 0, 0);
            }
        }

        // online softmax in log2 domain; lane owns rows w*32+mt*16+quad*4+r
#pragma unroll
        for (int mt = 0; mt < 2; ++mt) {
#pragma unroll
            for (int r = 0; r < 4; ++r) {
                float tv[8];
                float mb = -1e30f;
#pragma unroll
                for (int nt = 0; nt < 8; ++nt) {
                    tv[nt] = s[mt][nt][r] * C2LOG;
                    mb = fmaxf(mb, tv[nt]);
                }
#pragma unroll
                for (int off = 1; off < 16; off <<= 1)
                    mb = fmaxf(mb, __shfl_xor(mb, off));
                const float mn = fmaxf(m_run[mt][r], mb);
                const float alpha = exp2f(m_run[mt][r] - mn);
                m_run[mt][r] = mn;
                float ls = 0.f;
                bf16x8 pk;
#pragma unroll
                for (int nt = 0; nt < 8; ++nt) {
                    float p = exp2f(tv[nt] - mn);
                    ls += p;
                    pk[nt] = (__bf16)p;
                }
                const int prow = w * 32 + mt * 16 + quad * 4 + r;
                *(bf16x8*)&Pl[prow * P_STRIDE + l15 * 8] = pk;   // k' = l15*8+nt
#pragma unroll
                for (int off = 1; off < 16; off <<= 1)
                    ls += __shfl_xor(ls, off);
                l_run[mt][r] = l_run[mt][r] * alpha + ls;
#pragma unroll
                for (int d3 = 0; d3 < 3; ++d3)
                    o[mt][d3][r] *= alpha;
            }
        }

        __syncthreads();   // Vt + Pl ready

        // O += P V  (A = Pl[q][k'], B = Vt[d][k'])
        bf16x8 pa[2][4];
#pragma unroll
        for (int mt = 0; mt < 2; ++mt)
#pragma unroll
            for (int ks = 0; ks < 4; ++ks)
                pa[mt][ks] = *(const bf16x8*)&Pl[(w * 32 + mt * 16 + l15) * P_STRIDE + ks * 32 + quad * 8];
#pragma unroll
        for (int nt = 0; nt < 3; ++nt) {
#pragma unroll
            for (int ks = 0; ks < 4; ++ks) {
                bf16x8 vb = *(const bf16x8*)&Vt[(nt * 16 + l15) * VT_STRIDE + ks * 32 + quad * 8];
#pragma unroll
                for (int mt = 0; mt < 2; ++mt)
                    o[mt][nt] = __builtin_amdgcn_mfma_f32_16x16x32_bf16(pa[mt][ks], vb, o[mt][nt], 0, 0, 0);
            }
        }
    }

    // epilogue: Ctx[bh*49152 + row*48 + d] = o * (1/l)
#pragma unroll
    for (int mt = 0; mt < 2; ++mt) {
        float inv[4];
#pragma unroll
        for (int r = 0; r < 4; ++r)
            inv[r] = __builtin_amdgcn_rcpf(l_run[mt][r]);
#pragma unroll
        for (int nt = 0; nt < 3; ++nt) {
            const int d = nt * 16 + l15;
#pragma unroll
            for (int r = 0; r < 4; ++r) {
                const int row = qt * 128 + w * 32 + mt * 16 + quad * 4 + r;
                Ctx[qBase + (size_t)row * 48 + d] = (__bf16)(o[mt][nt][r] * inv[r]);
            }
        }
    }
}

// ---------- launch ----------
extern "C" void kernel_launch(void* const* d_in, const int* in_sizes, int n_in,
                              void* d_out, int out_size, void* d_ws, size_t ws_size,
                              hipStream_t stream) {
    const float* x    = (const float*)d_in[0];   // [8,1024,768]
    const float* Wqkv = (const float*)d_in[1];   // [768,2304]
    const float* Wo   = (const float*)d_in[2];   // [768,768]
    const float* bo   = (const float*)d_in[3];   // [768]
    float* out = (float*)d_out;                  // [8,1024,768]

    char* ws = (char*)d_ws;
    __bf16* Xbf    = (__bf16*)(ws + 0);                 // 8192*768
    __bf16* WqkvT  = (__bf16*)(ws + 12582912);          // 2304*768
    __bf16* WoT    = (__bf16*)(ws + 16121856);          // 768*768
    __bf16* Y1     = (__bf16*)(ws + 17301504);          // 8192*2304
    __bf16* Ctx    = (__bf16*)(ws + 55050240);          // 8192*768

    cvt_f32_bf16_kernel<<<6144, 256, 0, stream>>>(x, Xbf, 8192 * 768);
    transpose_f32_bf16_kernel<<<dim3(72, 24), dim3(32, 8), 0, stream>>>(Wqkv, WqkvT, 768, 2304);
    transpose_f32_bf16_kernel<<<dim3(24, 24), dim3(32, 8), 0, stream>>>(Wo, WoT, 768, 768);

    gemm_bt_kernel<true><<<dim3(18, 64), 256, 0, stream>>>(Xbf, WqkvT, Y1, nullptr, 8192, 2304, 768);

    attn_kernel<<<1024, 256, 0, stream>>>(Y1, Ctx);

    gemm_bt_kernel<false><<<dim3(6, 64), 256, 0, stream>>>(Ctx, WoT, out, bo, 8192, 768, 768);
}